// Round 6
// baseline (14318.294 us; speedup 1.0000x reference)
//
#include <hip/hip_runtime.h>
#include <math.h>
#include <float.h>

#define NUM_CB 8
#define CB_SIZE 256
#define DIM 128
#define BT (16 * 16384)   // 262144 tokens
#define Q_ELEMS ((size_t)BT * DIM)       // 33554432
#define I_ELEMS ((size_t)BT * NUM_CB)    // 2097152

// Inclusion margin for the ambiguity gate. Rigorous need ~5e-5
// (ref-pipeline differential 2*2.4e-5 + fast-chain 2.4e-6); 1.5e-4 = 3x.
#define MARGIN 1.5e-4f

// ---------------------------------------------------------------------------
// np.sum pairwise pattern for n=128 contiguous f32: 8 accumulators,
// acc_j = sum of elements j, j+8, ..., j+120, combined
// ((r0+r1)+(r2+r3))+((r4+r5)+(r6+r7)). Plain mul+add (no FMA) -> contract(off).
// Matches numpy's FLOAT_pairwise_sum 8-acc block bit-exactly.
// ---------------------------------------------------------------------------
__device__ __forceinline__ float np_sum_sq_128(const float* __restrict__ a) {
#pragma clang fp contract(off)
    float r0 = a[0] * a[0], r1 = a[1] * a[1], r2 = a[2] * a[2],
          r3 = a[3] * a[3], r4 = a[4] * a[4], r5 = a[5] * a[5],
          r6 = a[6] * a[6], r7 = a[7] * a[7];
#pragma unroll
    for (int i = 8; i < DIM; i += 8) {
        r0 = r0 + a[i + 0] * a[i + 0];
        r1 = r1 + a[i + 1] * a[i + 1];
        r2 = r2 + a[i + 2] * a[i + 2];
        r3 = r3 + a[i + 3] * a[i + 3];
        r4 = r4 + a[i + 4] * a[i + 4];
        r5 = r5 + a[i + 5] * a[i + 5];
        r6 = r6 + a[i + 6] * a[i + 6];
        r7 = r7 + a[i + 7] * a[i + 7];
    }
    return ((r0 + r1) + (r2 + r3)) + ((r4 + r5) + (r6 + r7));
}

// ---------------------------------------------------------------------------
// BLAS-class dot: ONE sequential FMA chain over d=0..127. This is the
// per-element accumulation order of OpenBLAS sgemm microkernels, Eigen gebp
// (XLA:CPU dot), oneDNN brgemm, and Tensile f32 VGPR accumulation -- the
// union of plausible refs if the np reference's einsum lowered to a GEMM.
// Dependent fmaf chain: compiler cannot reorder.
// ---------------------------------------------------------------------------
__device__ __forceinline__ float np_dot_seq_128(const float* __restrict__ x,
                                                const float* __restrict__ y) {
    float acc = 0.f;
#pragma unroll
    for (int d = 0; d < DIM; ++d) {
        acc = fmaf(x[d], y[d], acc);
    }
    return acc;
}

// Reference distance, bit-exact target: fl(fl(x_sq + e_sq) - fl(2*cross)).
__device__ __forceinline__ float np_dist_exact(const float* __restrict__ r,
                                               float x_sq_np, float esq_c,
                                               const float* __restrict__ e) {
#pragma clang fp contract(off)
    float cross = np_dot_seq_128(r, e);
    float S  = x_sq_np + esq_c;
    float t2 = 2.0f * cross;          // exact (x2)
    return S - t2;
}

// Fast score (order-free, fma): s = e_sq - 2*cross. Used only with MARGIN.
__device__ __forceinline__ float fast_score_128(const float* __restrict__ r,
                                                const float* __restrict__ e,
                                                float esq_c) {
    float b0 = 0.f, b1 = 0.f, b2 = 0.f, b3 = 0.f,
          b4 = 0.f, b5 = 0.f, b6 = 0.f, b7 = 0.f;
#pragma unroll
    for (int d = 0; d < DIM; d += 8) {
        b0 = fmaf(r[d + 0], e[d + 0], b0);
        b1 = fmaf(r[d + 1], e[d + 1], b1);
        b2 = fmaf(r[d + 2], e[d + 2], b2);
        b3 = fmaf(r[d + 3], e[d + 3], b3);
        b4 = fmaf(r[d + 4], e[d + 4], b4);
        b5 = fmaf(r[d + 5], e[d + 5], b5);
        b6 = fmaf(r[d + 6], e[d + 6], b6);
        b7 = fmaf(r[d + 7], e[d + 7], b7);
    }
    const float cross = ((b0 + b1) + (b2 + b3)) + ((b4 + b5) + (b6 + b7));
    return fmaf(-2.0f, cross, esq_c);
}

// ---------------------------------------------------------------------------
// e_sq matches np.sum(cb*cb, -1) bit-exactly (pairwise 8-acc, no FMA).
// ---------------------------------------------------------------------------
__global__ void rvq_esq_kernel(const float* __restrict__ cb,
                               float* __restrict__ esq) {
    int i = blockIdx.x * blockDim.x + threadIdx.x;   // 0 .. 2047
    if (i >= NUM_CB * CB_SIZE) return;
    esq[i] = np_sum_sq_128(cb + (size_t)i * DIM);
}

// ---------------------------------------------------------------------------
// Main RVQ kernel: one thread per token, residual in VGPRs.
// Pass A (fast fma): top-2 of s = e_sq - 2*cross.
// Gap > MARGIN: fast winner provably equals reference argmin.
// Else (rare): rescan; candidates within MARGIN get the emulated reference
// distance (f32, with x_sq, seq-FMA cross); first-index-min over those.
// ---------------------------------------------------------------------------
__global__ __launch_bounds__(256) void rvq_main_kernel(
    const float* __restrict__ z,
    const float* __restrict__ cb,
    const float* __restrict__ esq,
    float* __restrict__ out_q,
    float* __restrict__ out_idx,
    double* __restrict__ loss_acc) {

    const int tok = blockIdx.x * blockDim.x + threadIdx.x;   // < BT (exact grid)
    const float* zp = z + (size_t)tok * DIM;

    float r[DIM];
#pragma unroll
    for (int d = 0; d < DIM; d += 4) {
        float4 v = *reinterpret_cast<const float4*>(zp + d);
        r[d + 0] = v.x; r[d + 1] = v.y; r[d + 2] = v.z; r[d + 3] = v.w;
    }

    double lsum = 0.0;

    for (int k = 0; k < NUM_CB; ++k) {
        const float* cbk  = cb  + (size_t)k * CB_SIZE * DIM;
        const float* esqk = esq + k * CB_SIZE;

        // ---- Pass A: fast top-2 ----
        float min1 = FLT_MAX, min2 = FLT_MAX;
        int cmin = 0;
        for (int c = 0; c < CB_SIZE; ++c) {
            const float s = fast_score_128(r, cbk + (size_t)c * DIM, esqk[c]);
            if (s < min1) {
                min2 = min1; min1 = s; cmin = c;
            } else if (s < min2) {
                min2 = s;
            }
        }

        // ---- Pass B (rare): emulated-reference resolution ----
        if (!(min2 - min1 > MARGIN)) {
            const float x_sq_np = np_sum_sq_128(r);
            const float thr = min1 + MARGIN;
            float best = FLT_MAX;
            int cbest = 0;
            for (int c = 0; c < CB_SIZE; ++c) {
                const float* e = cbk + (size_t)c * DIM;
                const float s = fast_score_128(r, e, esqk[c]);
                if (s <= thr) {
                    const float dref = np_dist_exact(r, x_sq_np, esqk[c], e);
                    if (dref < best) { best = dref; cbest = c; }  // first-min
                }
            }
            cmin = cbest;
        }

        // gather chosen codeword, loss, residual update (elementwise fl(r-e))
        const float* e = cbk + (size_t)cmin * DIM;
        float l0 = 0.f, l1 = 0.f, l2 = 0.f, l3 = 0.f;
#pragma unroll
        for (int d = 0; d < DIM; d += 4) {
            float4 ev = *reinterpret_cast<const float4*>(e + d);
            float d0 = ev.x - r[d + 0];
            float d1 = ev.y - r[d + 1];
            float d2 = ev.z - r[d + 2];
            float d3 = ev.w - r[d + 3];
            l0 = fmaf(d0, d0, l0);
            l1 = fmaf(d1, d1, l1);
            l2 = fmaf(d2, d2, l2);
            l3 = fmaf(d3, d3, l3);
            r[d + 0] -= ev.x; r[d + 1] -= ev.y;
            r[d + 2] -= ev.z; r[d + 3] -= ev.w;
        }
        lsum += (double)((l0 + l1) + (l2 + l3));

        out_idx[(size_t)tok * NUM_CB + k] = (float)cmin;
    }

    // quantized = z + sg(quant_sum - z) == z - r_final (err ~1e-6 << 2% thr)
#pragma unroll
    for (int d = 0; d < DIM; d += 4) {
        float4 v = *reinterpret_cast<const float4*>(zp + d);
        float4 q;
        q.x = v.x - r[d + 0];
        q.y = v.y - r[d + 1];
        q.z = v.z - r[d + 2];
        q.w = v.w - r[d + 3];
        *reinterpret_cast<float4*>(out_q + (size_t)tok * DIM + d) = q;
    }

    // block-reduce loss, one atomic per block
    for (int off = 32; off > 0; off >>= 1)
        lsum += __shfl_down(lsum, off, 64);
    __shared__ double wsum[4];
    const int lane = threadIdx.x & 63;
    const int wid  = threadIdx.x >> 6;
    if (lane == 0) wsum[wid] = lsum;
    __syncthreads();
    if (threadIdx.x == 0) {
        atomicAdd(loss_acc, (wsum[0] + wsum[1]) + (wsum[2] + wsum[3]));
    }
}

__global__ void rvq_finalize_kernel(const double* __restrict__ loss_acc,
                                    float* __restrict__ out_loss) {
    // vq_loss = sum_k (mean + 0.25*mean) = 1.25 * total / (B*T*D)
    out_loss[0] = (float)(1.25 * loss_acc[0] / (double)Q_ELEMS);
}

extern "C" void kernel_launch(void* const* d_in, const int* in_sizes, int n_in,
                              void* d_out, int out_size, void* d_ws, size_t ws_size,
                              hipStream_t stream) {
    const float* z  = (const float*)d_in[0];
    const float* cb = (const float*)d_in[1];

    float* out_q    = (float*)d_out;
    float* out_idx  = out_q + Q_ELEMS;
    float* out_loss = out_idx + I_ELEMS;

    double* loss_acc = (double*)d_ws;
    float*  esq      = (float*)((char*)d_ws + 256);

    hipMemsetAsync(loss_acc, 0, sizeof(double), stream);
    rvq_esq_kernel<<<(NUM_CB * CB_SIZE + 255) / 256, 256, 0, stream>>>(cb, esq);
    rvq_main_kernel<<<BT / 256, 256, 0, stream>>>(z, cb, esq, out_q, out_idx,
                                                  loss_acc);
    rvq_finalize_kernel<<<1, 1, 0, stream>>>(loss_acc, out_loss);
}

// Round 7
// 12776.867 us; speedup vs baseline: 1.1206x; 1.1206x over previous
//
#include <hip/hip_runtime.h>
#include <math.h>
#include <float.h>

#define NUM_CB 8
#define CB_SIZE 256
#define DIM 128
#define D4 (DIM / 4)            // 32 float4s per vector
#define TC 64                   // candidates per LDS tile (32 KB)
#define NTILES (CB_SIZE / TC)   // 4
#define BT (16 * 16384)         // 262144 tokens
#define Q_ELEMS ((size_t)BT * DIM)       // 33554432
#define I_ELEMS ((size_t)BT * NUM_CB)    // 2097152

// Inclusion margin for the ambiguity gate (validated round 6).
#define MARGIN 1.5e-4f

// ---------------------------------------------------------------------------
// np.sum pairwise pattern, scalar version (esq kernel, global float*).
// 8 accumulators stride-8, plain mul+add (no FMA), fixed combine tree.
// ---------------------------------------------------------------------------
__device__ __forceinline__ float np_sum_sq_128(const float* __restrict__ a) {
#pragma clang fp contract(off)
    float r0 = 0.f, r1 = 0.f, r2 = 0.f, r3 = 0.f,
          r4 = 0.f, r5 = 0.f, r6 = 0.f, r7 = 0.f;
#pragma unroll
    for (int i = 0; i < DIM; i += 8) {
        r0 = r0 + a[i + 0] * a[i + 0];
        r1 = r1 + a[i + 1] * a[i + 1];
        r2 = r2 + a[i + 2] * a[i + 2];
        r3 = r3 + a[i + 3] * a[i + 3];
        r4 = r4 + a[i + 4] * a[i + 4];
        r5 = r5 + a[i + 5] * a[i + 5];
        r6 = r6 + a[i + 6] * a[i + 6];
        r7 = r7 + a[i + 7] * a[i + 7];
    }
    return ((r0 + r1) + (r2 + r3)) + ((r4 + r5) + (r6 + r7));
}

// Same arithmetic over the register-resident float4 residual (bit-identical
// mapping: acc_j covers d === j (mod 8); j<4 -> comp j of even i, j>=4 -> odd i).
__device__ __forceinline__ float np_sum_sq_128_v(const float4* r4v) {
#pragma clang fp contract(off)
    float a0 = 0.f, a1 = 0.f, a2 = 0.f, a3 = 0.f,
          a4 = 0.f, a5 = 0.f, a6 = 0.f, a7 = 0.f;
#pragma unroll
    for (int i = 0; i < D4; i += 2) {
        float4 x = r4v[i], y = r4v[i + 1];
        a0 = a0 + x.x * x.x; a1 = a1 + x.y * x.y;
        a2 = a2 + x.z * x.z; a3 = a3 + x.w * x.w;
        a4 = a4 + y.x * y.x; a5 = a5 + y.y * y.y;
        a6 = a6 + y.z * y.z; a7 = a7 + y.w * y.w;
    }
    return ((a0 + a1) + (a2 + a3)) + ((a4 + a5) + (a6 + a7));
}

// BLAS-class sequential FMA dot over d=0..127 (validated round 6).
__device__ __forceinline__ float np_dot_seq_128_v(const float4* r4v,
                                                  const float* __restrict__ e) {
    const float4* e4 = reinterpret_cast<const float4*>(e);
    float acc = 0.f;
#pragma unroll
    for (int i = 0; i < D4; ++i) {
        float4 ev = e4[i];
        acc = fmaf(r4v[i].x, ev.x, acc);
        acc = fmaf(r4v[i].y, ev.y, acc);
        acc = fmaf(r4v[i].z, ev.z, acc);
        acc = fmaf(r4v[i].w, ev.w, acc);
    }
    return acc;
}

// Reference distance: fl(fl(x_sq + e_sq) - fl(2*cross_seq)).
__device__ __forceinline__ float np_dist_exact_v(const float4* r4v,
                                                 float x_sq_np, float esq_c,
                                                 const float* __restrict__ e) {
#pragma clang fp contract(off)
    float cross = np_dot_seq_128_v(r4v, e);
    float S  = x_sq_np + esq_c;
    float t2 = 2.0f * cross;
    return S - t2;
}

// Fast score over float4s, 8-acc fma chains + fixed combine. Used by Pass A
// (LDS source) and Pass B rescan (global source) -- identical arithmetic on
// identical bits -> identical results.
__device__ __forceinline__ float fast_score_v(const float4* r4v,
                                              const float4* e4, float esq_c) {
    float b0 = 0.f, b1 = 0.f, b2 = 0.f, b3 = 0.f,
          b4 = 0.f, b5 = 0.f, b6 = 0.f, b7 = 0.f;
#pragma unroll
    for (int i = 0; i < D4; i += 2) {
        float4 e0 = e4[i], e1 = e4[i + 1];
        b0 = fmaf(r4v[i].x,     e0.x, b0);
        b1 = fmaf(r4v[i].y,     e0.y, b1);
        b2 = fmaf(r4v[i].z,     e0.z, b2);
        b3 = fmaf(r4v[i].w,     e0.w, b3);
        b4 = fmaf(r4v[i + 1].x, e1.x, b4);
        b5 = fmaf(r4v[i + 1].y, e1.y, b5);
        b6 = fmaf(r4v[i + 1].z, e1.z, b6);
        b7 = fmaf(r4v[i + 1].w, e1.w, b7);
    }
    const float cross = ((b0 + b1) + (b2 + b3)) + ((b4 + b5) + (b6 + b7));
    return fmaf(-2.0f, cross, esq_c);
}

// ---------------------------------------------------------------------------
// e_sq matches np.sum(cb*cb, -1) bit-exactly.
// ---------------------------------------------------------------------------
__global__ void rvq_esq_kernel(const float* __restrict__ cb,
                               float* __restrict__ esq) {
    int i = blockIdx.x * blockDim.x + threadIdx.x;   // 0 .. 2047
    if (i >= NUM_CB * CB_SIZE) return;
    esq[i] = np_sum_sq_128(cb + (size_t)i * DIM);
}

// ---------------------------------------------------------------------------
// Main RVQ kernel. One token per thread; residual in 32 float4 VGPRs.
// Pass A streams 64-candidate codebook tiles through LDS (broadcast
// ds_read_b128, conflict-free) -> v_fmac-bound inner loop.
// Pass B (rare, margin-gated) re-resolves ambiguous argmins with the
// bit-exact np-emulated distance (validated round 6).
// ---------------------------------------------------------------------------
__global__ __launch_bounds__(256) void rvq_main_kernel(
    const float* __restrict__ z,
    const float* __restrict__ cb,
    const float* __restrict__ esq,
    float* __restrict__ out_q,
    float* __restrict__ out_idx,
    double* __restrict__ loss_acc) {

    __shared__ float4 se[TC * D4];     // 32 KB candidate tile
    __shared__ float  sesq[CB_SIZE];   // 1 KB e_sq for current codebook

    const int tid = threadIdx.x;
    const int tok = blockIdx.x * blockDim.x + tid;   // exact grid
    const float4* zp4 = reinterpret_cast<const float4*>(z + (size_t)tok * DIM);

    float4 r4[D4];
#pragma unroll
    for (int i = 0; i < D4; ++i) r4[i] = zp4[i];

    double lsum = 0.0;

    for (int k = 0; k < NUM_CB; ++k) {
        const float* cbk  = cb  + (size_t)k * CB_SIZE * DIM;
        const float* esqk = esq + k * CB_SIZE;

        float min1 = FLT_MAX, min2 = FLT_MAX;
        int cmin = 0;

        for (int tile = 0; tile < NTILES; ++tile) {
            __syncthreads();   // previous tile fully consumed
            const float4* gsrc = reinterpret_cast<const float4*>(cbk)
                                 + (size_t)tile * TC * D4;
#pragma unroll
            for (int i = 0; i < (TC * D4) / 256; ++i)   // 8 float4 / thread
                se[tid + i * 256] = gsrc[tid + i * 256];
            if (tile == 0) sesq[tid] = esqk[tid];       // uniform branch
            __syncthreads();

            for (int cc = 0; cc < TC; ++cc) {
                const int c = tile * TC + cc;
                const float s = fast_score_v(r4, &se[cc * D4], sesq[c]);
                if (s < min1) {
                    min2 = min1; min1 = s; cmin = c;
                } else if (s < min2) {
                    min2 = s;
                }
            }
        }

        // ---- Pass B (rare): bit-exact np-emulated resolution ----
        if (!(min2 - min1 > MARGIN)) {
            const float x_sq_np = np_sum_sq_128_v(r4);
            const float thr = min1 + MARGIN;
            float best = FLT_MAX;
            int cbest = 0;
            for (int c = 0; c < CB_SIZE; ++c) {
                const float* e = cbk + (size_t)c * DIM;
                const float s = fast_score_v(
                    r4, reinterpret_cast<const float4*>(e), esqk[c]);
                if (s <= thr) {
                    const float dref = np_dist_exact_v(r4, x_sq_np, esqk[c], e);
                    if (dref < best) { best = dref; cbest = c; }  // first-min
                }
            }
            cmin = cbest;
        }

        // gather chosen codeword, loss, residual update (elementwise fl(r-e))
        const float4* e4 = reinterpret_cast<const float4*>(
            cbk + (size_t)cmin * DIM);
        float l0 = 0.f, l1 = 0.f, l2 = 0.f, l3 = 0.f;
#pragma unroll
        for (int i = 0; i < D4; ++i) {
            float4 ev = e4[i];
            float d0 = ev.x - r4[i].x;
            float d1 = ev.y - r4[i].y;
            float d2 = ev.z - r4[i].z;
            float d3 = ev.w - r4[i].w;
            l0 = fmaf(d0, d0, l0);
            l1 = fmaf(d1, d1, l1);
            l2 = fmaf(d2, d2, l2);
            l3 = fmaf(d3, d3, l3);
            r4[i].x -= ev.x; r4[i].y -= ev.y;
            r4[i].z -= ev.z; r4[i].w -= ev.w;
        }
        lsum += (double)((l0 + l1) + (l2 + l3));

        out_idx[(size_t)tok * NUM_CB + k] = (float)cmin;
    }

    // quantized = z + sg(quant_sum - z) == z - r_final (err ~1e-6 << 2% thr)
    float4* oq4 = reinterpret_cast<float4*>(out_q + (size_t)tok * DIM);
#pragma unroll
    for (int i = 0; i < D4; ++i) {
        float4 v = zp4[i];
        float4 q;
        q.x = v.x - r4[i].x; q.y = v.y - r4[i].y;
        q.z = v.z - r4[i].z; q.w = v.w - r4[i].w;
        oq4[i] = q;
    }

    // block-reduce loss, one atomic per block
    for (int off = 32; off > 0; off >>= 1)
        lsum += __shfl_down(lsum, off, 64);
    __shared__ double wsum[4];
    const int lane = tid & 63;
    const int wid  = tid >> 6;
    if (lane == 0) wsum[wid] = lsum;
    __syncthreads();
    if (tid == 0) {
        atomicAdd(loss_acc, (wsum[0] + wsum[1]) + (wsum[2] + wsum[3]));
    }
}

__global__ void rvq_finalize_kernel(const double* __restrict__ loss_acc,
                                    float* __restrict__ out_loss) {
    // vq_loss = sum_k (mean + 0.25*mean) = 1.25 * total / (B*T*D)
    out_loss[0] = (float)(1.25 * loss_acc[0] / (double)Q_ELEMS);
}

extern "C" void kernel_launch(void* const* d_in, const int* in_sizes, int n_in,
                              void* d_out, int out_size, void* d_ws, size_t ws_size,
                              hipStream_t stream) {
    const float* z  = (const float*)d_in[0];
    const float* cb = (const float*)d_in[1];

    float* out_q    = (float*)d_out;
    float* out_idx  = out_q + Q_ELEMS;
    float* out_loss = out_idx + I_ELEMS;

    double* loss_acc = (double*)d_ws;
    float*  esq      = (float*)((char*)d_ws + 256);

    hipMemsetAsync(loss_acc, 0, sizeof(double), stream);
    rvq_esq_kernel<<<(NUM_CB * CB_SIZE + 255) / 256, 256, 0, stream>>>(cb, esq);
    rvq_main_kernel<<<BT / 256, 256, 0, stream>>>(z, cb, esq, out_q, out_idx,
                                                  loss_acc);
    rvq_finalize_kernel<<<1, 1, 0, stream>>>(loss_acc, out_loss);
}

// Round 8
// 2239.001 us; speedup vs baseline: 6.3949x; 5.7065x over previous
//
#include <hip/hip_runtime.h>
#include <math.h>
#include <float.h>

#define NUM_CB 8
#define CB_SIZE 256
#define DIM 128
#define BT (16 * 16384)                  // 262144 tokens
#define Q_ELEMS ((size_t)BT * DIM)       // 33554432
#define I_ELEMS ((size_t)BT * NUM_CB)    // 2097152

// Pass-A ambiguity margin: |passA - true| <= ~3e-5, |ref - true| differential
// <= ~3.3e-5  =>  need ~6.5e-5; 1.5e-4 gives 2.3x safety. Gate rate ~0.8%.
#define MARGIN_A 1.5e-4f

typedef short  bf16x8 __attribute__((ext_vector_type(8)));
typedef float  f32x4  __attribute__((ext_vector_type(4)));

// ---------------------------------------------------------------------------
// bf16 helpers (RNE). Any deterministic split works (margin covers it).
// ---------------------------------------------------------------------------
__device__ __forceinline__ unsigned short bf16_rne(float f) {
    unsigned int u = __float_as_uint(f);
    u = u + 0x7FFFu + ((u >> 16) & 1u);
    return (unsigned short)(u >> 16);
}
__device__ __forceinline__ float bf16_tof(unsigned short h) {
    return __uint_as_float(((unsigned int)h) << 16);
}

// ---------------------------------------------------------------------------
// VALIDATED (round 6/7) np emulation: pairwise-8 sum-of-squares, no FMA.
// ---------------------------------------------------------------------------
__device__ __forceinline__ float np_sum_sq_128(const float* a) {
#pragma clang fp contract(off)
    float r0 = 0.f, r1 = 0.f, r2 = 0.f, r3 = 0.f,
          r4 = 0.f, r5 = 0.f, r6 = 0.f, r7 = 0.f;
#pragma unroll
    for (int i = 0; i < DIM; i += 8) {
        r0 = r0 + a[i + 0] * a[i + 0];
        r1 = r1 + a[i + 1] * a[i + 1];
        r2 = r2 + a[i + 2] * a[i + 2];
        r3 = r3 + a[i + 3] * a[i + 3];
        r4 = r4 + a[i + 4] * a[i + 4];
        r5 = r5 + a[i + 5] * a[i + 5];
        r6 = r6 + a[i + 6] * a[i + 6];
        r7 = r7 + a[i + 7] * a[i + 7];
    }
    return ((r0 + r1) + (r2 + r3)) + ((r4 + r5) + (r6 + r7));
}

// VALIDATED: reference distance = fl(fl(x_sq+e_sq) - fl(2*cross_seqfma)).
__device__ __forceinline__ float np_dist_lds(const float4* rb4, float xs,
                                             float esq_c,
                                             const float* __restrict__ e) {
#pragma clang fp contract(off)
    float acc = 0.f;
#pragma unroll
    for (int i = 0; i < 32; ++i) {
        float4 rv = rb4[i];
        float4 ev = *reinterpret_cast<const float4*>(e + 4 * i);
        acc = fmaf(rv.x, ev.x, acc);
        acc = fmaf(rv.y, ev.y, acc);
        acc = fmaf(rv.z, ev.z, acc);
        acc = fmaf(rv.w, ev.w, acc);
    }
    float S  = xs + esq_c;
    float t2 = 2.0f * acc;
    return S - t2;
}

// ---------------------------------------------------------------------------
// e_sq = np.sum(cb*cb, -1), bit-exact.
// ---------------------------------------------------------------------------
__global__ void rvq_esq_kernel(const float* __restrict__ cb,
                               float* __restrict__ esq) {
    int i = blockIdx.x * blockDim.x + threadIdx.x;   // 0 .. 2047
    if (i >= NUM_CB * CB_SIZE) return;
    esq[i] = np_sum_sq_128(cb + (size_t)i * DIM);
}

// ---------------------------------------------------------------------------
// Main kernel: 64 tokens/block (4 waves x 16). Residual distributed:
// lane (q = lane>>4, lrow = lane&15) owns token lrow's dims {32s+8q+i}.
// Pass A: mfma_f32_16x16x32_bf16, 3 split-products, LDS bf16 hi/lo planes.
// Pass B (gap <= margin): wave-cooperative EXACT np argmin.
// ---------------------------------------------------------------------------
__global__ __launch_bounds__(256) void rvq_mfma_kernel(
    const float* __restrict__ z,
    const float* __restrict__ cb,
    const float* __restrict__ esq,
    float* __restrict__ out_q,
    float* __restrict__ out_idx,
    double* __restrict__ loss_acc) {

    __shared__ bf16x8 s_eh[64 * 16];                 // 16 KB hi plane
    __shared__ bf16x8 s_el[64 * 16];                 // 16 KB lo plane
    __shared__ __align__(16) float s_rbuf[4][DIM];   // per-wave passB residual
    __shared__ float s_m1[4][16], s_m2[4][16];
    __shared__ int   s_cmin[4][16];

    const int tid  = threadIdx.x;
    const int wid  = tid >> 6;
    const int lane = tid & 63;
    const int lrow = lane & 15;       // token-in-wave (A) / col (B,C)
    const int lq   = lane >> 4;       // k-chunk group
    const int tokw = blockIdx.x * 64 + wid * 16;     // wave's first token
    const int tok  = tokw + lrow;                    // lane's owned token

    // ---- load residual chunks: r[s][i] = z[tok][32s + 8lq + i] ----
    float r[4][8];
    {
        const float* zp = z + (size_t)tok * DIM + 8 * lq;
#pragma unroll
        for (int s = 0; s < 4; ++s) {
            float4 a = *reinterpret_cast<const float4*>(zp + 32 * s);
            float4 b = *reinterpret_cast<const float4*>(zp + 32 * s + 4);
            r[s][0] = a.x; r[s][1] = a.y; r[s][2] = a.z; r[s][3] = a.w;
            r[s][4] = b.x; r[s][5] = b.y; r[s][6] = b.z; r[s][7] = b.w;
        }
    }

    double lsum = 0.0;

    for (int k = 0; k < NUM_CB; ++k) {
        const float* cbk  = cb  + (size_t)k * CB_SIZE * DIM;
        const float* esqk = esq + k * CB_SIZE;

        // ---- split residual into bf16 hi/mid A-fragments ----
        bf16x8 ah[4], am[4];
#pragma unroll
        for (int s = 0; s < 4; ++s) {
#pragma unroll
            for (int i = 0; i < 8; ++i) {
                unsigned short h = bf16_rne(r[s][i]);
                float rem = r[s][i] - bf16_tof(h);
                unsigned short m = bf16_rne(rem);
                ah[s][i] = (short)h;
                am[s][i] = (short)m;
            }
        }

        float m1[4], m2[4];
        int   i1[4];
#pragma unroll
        for (int j = 0; j < 4; ++j) { m1[j] = FLT_MAX; m2[j] = FLT_MAX; i1[j] = 0x7fffffff; }

        for (int T = 0; T < 4; ++T) {         // 64-candidate tiles
            __syncthreads();
            // stage + convert: 4 slots (8 elems each) per thread
#pragma unroll
            for (int w = 0; w < 4; ++w) {
                int idx  = tid + w * 256;     // 0..1023
                int cand = idx >> 4;
                int slot = idx & 15;
                const float* src = cbk + (size_t)(T * 64 + cand) * DIM + slot * 8;
                float4 a = *reinterpret_cast<const float4*>(src);
                float4 b = *reinterpret_cast<const float4*>(src + 4);
                float e[8] = {a.x, a.y, a.z, a.w, b.x, b.y, b.z, b.w};
                bf16x8 eh, el;
#pragma unroll
                for (int i = 0; i < 8; ++i) {
                    unsigned short h = bf16_rne(e[i]);
                    float rem = e[i] - bf16_tof(h);
                    eh[i] = (short)h;
                    el[i] = (short)bf16_rne(rem);
                }
                int ds = slot ^ (cand & 15);
                s_eh[cand * 16 + ds] = eh;
                s_el[cand * 16 + ds] = el;
            }
            __syncthreads();

            for (int ct = 0; ct < 4; ++ct) {  // 16-candidate column tiles
                const int cbase = ct * 16 + lrow;    // tile-local cand of lane
                bf16x8 bh[4], bl[4];
#pragma unroll
                for (int s = 0; s < 4; ++s) {
                    int ls = (4 * s + lq) ^ lrow;
                    bh[s] = s_eh[cbase * 16 + ls];
                    bl[s] = s_el[cbase * 16 + ls];
                }
                f32x4 acc0 = {0.f, 0.f, 0.f, 0.f};
                f32x4 acc1 = {0.f, 0.f, 0.f, 0.f};
                // rh*eh
                acc0 = __builtin_amdgcn_mfma_f32_16x16x32_bf16(ah[0], bh[0], acc0, 0, 0, 0);
                acc0 = __builtin_amdgcn_mfma_f32_16x16x32_bf16(ah[1], bh[1], acc0, 0, 0, 0);
                acc1 = __builtin_amdgcn_mfma_f32_16x16x32_bf16(ah[2], bh[2], acc1, 0, 0, 0);
                acc1 = __builtin_amdgcn_mfma_f32_16x16x32_bf16(ah[3], bh[3], acc1, 0, 0, 0);
                // rm*eh
                acc0 = __builtin_amdgcn_mfma_f32_16x16x32_bf16(am[0], bh[0], acc0, 0, 0, 0);
                acc0 = __builtin_amdgcn_mfma_f32_16x16x32_bf16(am[1], bh[1], acc0, 0, 0, 0);
                acc1 = __builtin_amdgcn_mfma_f32_16x16x32_bf16(am[2], bh[2], acc1, 0, 0, 0);
                acc1 = __builtin_amdgcn_mfma_f32_16x16x32_bf16(am[3], bh[3], acc1, 0, 0, 0);
                // rh*el
                acc0 = __builtin_amdgcn_mfma_f32_16x16x32_bf16(ah[0], bl[0], acc0, 0, 0, 0);
                acc0 = __builtin_amdgcn_mfma_f32_16x16x32_bf16(ah[1], bl[1], acc0, 0, 0, 0);
                acc1 = __builtin_amdgcn_mfma_f32_16x16x32_bf16(ah[2], bl[2], acc1, 0, 0, 0);
                acc1 = __builtin_amdgcn_mfma_f32_16x16x32_bf16(ah[3], bl[3], acc1, 0, 0, 0);

                const int c = T * 64 + ct * 16 + lrow;      // global candidate
                const float esq_c = esqk[c];
#pragma unroll
                for (int j = 0; j < 4; ++j) {
                    float s = fmaf(-2.0f, acc0[j] + acc1[j], esq_c);
                    if (s < m1[j]) {
                        m2[j] = m1[j]; m1[j] = s; i1[j] = c;
                    } else if (s < m2[j]) {
                        m2[j] = s;
                    }
                }
            }
        }

        // ---- cross-lane top-2 lexicographic reduce (within 16-lane group) --
#pragma unroll
        for (int d = 1; d < 16; d <<= 1) {
#pragma unroll
            for (int j = 0; j < 4; ++j) {
                float om1 = __shfl_xor(m1[j], d);
                float om2 = __shfl_xor(m2[j], d);
                int   oi1 = __shfl_xor(i1[j], d);
                bool ow = (om1 < m1[j]) || (om1 == m1[j] && oi1 < i1[j]);
                float w1 = ow ? om1 : m1[j];
                int   wi = ow ? oi1 : i1[j];
                float lo = ow ? m1[j] : om1;
                float w2 = fminf(fminf(m2[j], om2), lo);
                m1[j] = w1; i1[j] = wi; m2[j] = w2;
            }
        }

        // writers: lane 16*lq + lrow (lrow<4) owns token 4*lq + lrow (= reg lrow)
        if (lrow < 4) {
            float wm1 = lrow == 0 ? m1[0] : lrow == 1 ? m1[1] : lrow == 2 ? m1[2] : m1[3];
            float wm2 = lrow == 0 ? m2[0] : lrow == 1 ? m2[1] : lrow == 2 ? m2[2] : m2[3];
            int   wc  = lrow == 0 ? i1[0] : lrow == 1 ? i1[1] : lrow == 2 ? i1[2] : i1[3];
            int t = 4 * lq + lrow;
            s_m1[wid][t] = wm1;
            s_m2[wid][t] = wm2;
            s_cmin[wid][t] = wc;
        }
        asm volatile("s_waitcnt lgkmcnt(0)" ::: "memory");

        // ---- Pass B: exact np argmin for ambiguous tokens (wave-coop) ----
        float g1 = s_m1[wid][lrow];
        float g2 = s_m2[wid][lrow];
        bool amb = (lane < 16) && !(g2 - g1 > MARGIN_A);
        unsigned long long mask = __ballot(amb);
        while (mask) {
            int srct = __ffsll(mask) - 1;     // token index 0..15
            mask &= mask - 1;
            if (lrow == srct) {               // 4 owner lanes stage residual
#pragma unroll
                for (int s = 0; s < 4; ++s) {
                    float4* dst = reinterpret_cast<float4*>(
                        &s_rbuf[wid][32 * s + 8 * lq]);
                    dst[0] = make_float4(r[s][0], r[s][1], r[s][2], r[s][3]);
                    dst[1] = make_float4(r[s][4], r[s][5], r[s][6], r[s][7]);
                }
            }
            asm volatile("s_waitcnt lgkmcnt(0)" ::: "memory");
            float xs = 0.f;
            if (lane == 0) xs = np_sum_sq_128(&s_rbuf[wid][0]);
            xs = __shfl(xs, 0);
            const float4* rb4 = reinterpret_cast<const float4*>(&s_rbuf[wid][0]);
            float bd = FLT_MAX;
            int   bc = 0x7fffffff;
#pragma unroll
            for (int ii = 0; ii < 4; ++ii) {
                int c = lane + 64 * ii;
                float dref = np_dist_lds(rb4, xs, esqk[c], cbk + (size_t)c * DIM);
                if (dref < bd || (dref == bd && c < bc)) { bd = dref; bc = c; }
            }
#pragma unroll
            for (int d = 1; d < 64; d <<= 1) {
                float od = __shfl_xor(bd, d);
                int   oc = __shfl_xor(bc, d);
                if (od < bd || (od == bd && oc < bc)) { bd = od; bc = oc; }
            }
            if (lane == 0) s_cmin[wid][srct] = bc;
            asm volatile("s_waitcnt lgkmcnt(0)" ::: "memory");
        }

        // ---- outputs + residual update ----
        if (lane < 16)
            out_idx[(size_t)(tokw + lane) * NUM_CB + k] = (float)s_cmin[wid][lane];

        const int cm = s_cmin[wid][lrow];
        const float* ep = cbk + (size_t)cm * DIM + 8 * lq;
        float l0 = 0.f, l1 = 0.f, l2 = 0.f, l3 = 0.f;
#pragma unroll
        for (int s = 0; s < 4; ++s) {
            float4 ev0 = *reinterpret_cast<const float4*>(ep + 32 * s);
            float4 ev1 = *reinterpret_cast<const float4*>(ep + 32 * s + 4);
            float d0 = ev0.x - r[s][0], d1 = ev0.y - r[s][1];
            float d2 = ev0.z - r[s][2], d3 = ev0.w - r[s][3];
            float d4 = ev1.x - r[s][4], d5 = ev1.y - r[s][5];
            float d6 = ev1.z - r[s][6], d7 = ev1.w - r[s][7];
            l0 = fmaf(d0, d0, l0); l1 = fmaf(d1, d1, l1);
            l2 = fmaf(d2, d2, l2); l3 = fmaf(d3, d3, l3);
            l0 = fmaf(d4, d4, l0); l1 = fmaf(d5, d5, l1);
            l2 = fmaf(d6, d6, l2); l3 = fmaf(d7, d7, l3);
            r[s][0] -= ev0.x; r[s][1] -= ev0.y; r[s][2] -= ev0.z; r[s][3] -= ev0.w;
            r[s][4] -= ev1.x; r[s][5] -= ev1.y; r[s][6] -= ev1.z; r[s][7] -= ev1.w;
        }
        lsum += (double)((l0 + l1) + (l2 + l3));
    }

    // ---- quantized = z - r_final ----
    {
        const float* zp = z + (size_t)tok * DIM + 8 * lq;
        float* op = out_q + (size_t)tok * DIM + 8 * lq;
#pragma unroll
        for (int s = 0; s < 4; ++s) {
            float4 a = *reinterpret_cast<const float4*>(zp + 32 * s);
            float4 b = *reinterpret_cast<const float4*>(zp + 32 * s + 4);
            float4 qa = make_float4(a.x - r[s][0], a.y - r[s][1],
                                    a.z - r[s][2], a.w - r[s][3]);
            float4 qb = make_float4(b.x - r[s][4], b.y - r[s][5],
                                    b.z - r[s][6], b.w - r[s][7]);
            *reinterpret_cast<float4*>(op + 32 * s)     = qa;
            *reinterpret_cast<float4*>(op + 32 * s + 4) = qb;
        }
    }

    // ---- loss reduction ----
    for (int off = 32; off > 0; off >>= 1)
        lsum += __shfl_down(lsum, off, 64);
    __shared__ double wsum[4];
    if (lane == 0) wsum[wid] = lsum;
    __syncthreads();
    if (tid == 0)
        atomicAdd(loss_acc, (wsum[0] + wsum[1]) + (wsum[2] + wsum[3]));
}

__global__ void rvq_finalize_kernel(const double* __restrict__ loss_acc,
                                    float* __restrict__ out_loss) {
    out_loss[0] = (float)(1.25 * loss_acc[0] / (double)Q_ELEMS);
}

extern "C" void kernel_launch(void* const* d_in, const int* in_sizes, int n_in,
                              void* d_out, int out_size, void* d_ws, size_t ws_size,
                              hipStream_t stream) {
    const float* z  = (const float*)d_in[0];
    const float* cb = (const float*)d_in[1];

    float* out_q    = (float*)d_out;
    float* out_idx  = out_q + Q_ELEMS;
    float* out_loss = out_idx + I_ELEMS;

    double* loss_acc = (double*)d_ws;
    float*  esq      = (float*)((char*)d_ws + 256);

    hipMemsetAsync(loss_acc, 0, sizeof(double), stream);
    rvq_esq_kernel<<<(NUM_CB * CB_SIZE + 255) / 256, 256, 0, stream>>>(cb, esq);
    rvq_mfma_kernel<<<BT / 64, 256, 0, stream>>>(z, cb, esq, out_q, out_idx,
                                                 loss_acc);
    rvq_finalize_kernel<<<1, 1, 0, stream>>>(loss_acc, out_loss);
}

// Round 9
// 2035.860 us; speedup vs baseline: 7.0330x; 1.0998x over previous
//
#include <hip/hip_runtime.h>
#include <math.h>
#include <float.h>

#define NUM_CB 8
#define CB_SIZE 256
#define DIM 128
#define BT (16 * 16384)                  // 262144 tokens
#define Q_ELEMS ((size_t)BT * DIM)       // 33554432
#define I_ELEMS ((size_t)BT * NUM_CB)    // 2097152

// Pass-A ambiguity margin (validated rounds 6-8): |passA - true| <= ~3e-5,
// |ref - true| differential <= ~3.3e-5 => need ~6.5e-5; 1.5e-4 = 2.3x safety.
#define MARGIN_A 1.5e-4f

typedef short  bf16x8 __attribute__((ext_vector_type(8)));
typedef float  f32x4  __attribute__((ext_vector_type(4)));

// ---------------------------------------------------------------------------
// bf16 helpers (RNE).
// ---------------------------------------------------------------------------
__device__ __forceinline__ unsigned short bf16_rne(float f) {
    unsigned int u = __float_as_uint(f);
    u = u + 0x7FFFu + ((u >> 16) & 1u);
    return (unsigned short)(u >> 16);
}
__device__ __forceinline__ float bf16_tof(unsigned short h) {
    return __uint_as_float(((unsigned int)h) << 16);
}

// ---------------------------------------------------------------------------
// VALIDATED (rounds 6-8) np emulation: pairwise-8 sum-of-squares, no FMA.
// ---------------------------------------------------------------------------
__device__ __forceinline__ float np_sum_sq_128(const float* a) {
#pragma clang fp contract(off)
    float r0 = 0.f, r1 = 0.f, r2 = 0.f, r3 = 0.f,
          r4 = 0.f, r5 = 0.f, r6 = 0.f, r7 = 0.f;
#pragma unroll
    for (int i = 0; i < DIM; i += 8) {
        r0 = r0 + a[i + 0] * a[i + 0];
        r1 = r1 + a[i + 1] * a[i + 1];
        r2 = r2 + a[i + 2] * a[i + 2];
        r3 = r3 + a[i + 3] * a[i + 3];
        r4 = r4 + a[i + 4] * a[i + 4];
        r5 = r5 + a[i + 5] * a[i + 5];
        r6 = r6 + a[i + 6] * a[i + 6];
        r7 = r7 + a[i + 7] * a[i + 7];
    }
    return ((r0 + r1) + (r2 + r3)) + ((r4 + r5) + (r6 + r7));
}

// VALIDATED: reference distance = fl(fl(x_sq+e_sq) - fl(2*cross_seqfma)).
__device__ __forceinline__ float np_dist_lds(const float4* rb4, float xs,
                                             float esq_c,
                                             const float* __restrict__ e) {
#pragma clang fp contract(off)
    float acc = 0.f;
#pragma unroll
    for (int i = 0; i < 32; ++i) {
        float4 rv = rb4[i];
        float4 ev = *reinterpret_cast<const float4*>(e + 4 * i);
        acc = fmaf(rv.x, ev.x, acc);
        acc = fmaf(rv.y, ev.y, acc);
        acc = fmaf(rv.z, ev.z, acc);
        acc = fmaf(rv.w, ev.w, acc);
    }
    float S  = xs + esq_c;
    float t2 = 2.0f * acc;
    return S - t2;
}

// ---------------------------------------------------------------------------
// e_sq = np.sum(cb*cb, -1), bit-exact.
// ---------------------------------------------------------------------------
__global__ void rvq_esq_kernel(const float* __restrict__ cb,
                               float* __restrict__ esq) {
    int i = blockIdx.x * blockDim.x + threadIdx.x;   // 0 .. 2047
    if (i >= NUM_CB * CB_SIZE) return;
    esq[i] = np_sum_sq_128(cb + (size_t)i * DIM);
}

// ---------------------------------------------------------------------------
// Precompute bf16 hi/lo planes of all codebooks, stored in the EXACT swizzled
// LDS tile image: plane[(k*4+T)*1024 + cand*16 + (slot ^ (cand&15))].
// One-time cost (~32K items); removes all conversion VALU from the hot loop.
// ---------------------------------------------------------------------------
__global__ void rvq_split_kernel(const float* __restrict__ cb,
                                 bf16x8* __restrict__ g_eh,
                                 bf16x8* __restrict__ g_el) {
    int idx = blockIdx.x * blockDim.x + threadIdx.x;   // 0 .. 32767
    if (idx >= NUM_CB * CB_SIZE * 16) return;
    int slot = idx & 15;
    int cand = (idx >> 4) & 63;
    int tk   = idx >> 10;                 // k*4 + T, 0..31
    const float* src = cb + ((size_t)tk * 64 + cand) * DIM + slot * 8;
    float4 a = *reinterpret_cast<const float4*>(src);
    float4 b = *reinterpret_cast<const float4*>(src + 4);
    float e[8] = {a.x, a.y, a.z, a.w, b.x, b.y, b.z, b.w};
    bf16x8 eh, el;
#pragma unroll
    for (int i = 0; i < 8; ++i) {
        unsigned short h = bf16_rne(e[i]);
        float rem = e[i] - bf16_tof(h);
        eh[i] = (short)h;
        el[i] = (short)bf16_rne(rem);
    }
    int ds = slot ^ (cand & 15);
    g_eh[(size_t)tk * 1024 + cand * 16 + ds] = eh;
    g_el[(size_t)tk * 1024 + cand * 16 + ds] = el;
}

// ---------------------------------------------------------------------------
// Main kernel: 64 tokens/block (4 waves x 16). Residual distributed:
// lane (lq = lane>>4, lrow = lane&15) owns token lrow's dims {32s+8lq+i}.
// Pass A: mfma_f32_16x16x32_bf16, 3 split-products; B-planes staged to LDS
// by plain float4 copy from the precomputed swizzled image.
// Pass B (gap <= margin): wave-cooperative EXACT np argmin (validated).
// ---------------------------------------------------------------------------
__global__ __launch_bounds__(256) void rvq_mfma_kernel(
    const float* __restrict__ z,
    const float* __restrict__ cb,
    const float* __restrict__ esq,
    const bf16x8* __restrict__ g_eh,
    const bf16x8* __restrict__ g_el,
    float* __restrict__ out_q,
    float* __restrict__ out_idx,
    double* __restrict__ loss_acc) {

    __shared__ bf16x8 s_eh[64 * 16];                 // 16 KB hi plane
    __shared__ bf16x8 s_el[64 * 16];                 // 16 KB lo plane
    __shared__ __align__(16) float s_rbuf[4][DIM];   // per-wave passB residual
    __shared__ float s_m1[4][16], s_m2[4][16];
    __shared__ int   s_cmin[4][16];

    const int tid  = threadIdx.x;
    const int wid  = tid >> 6;
    const int lane = tid & 63;
    const int lrow = lane & 15;       // token-in-wave (A) / col (B,C)
    const int lq   = lane >> 4;       // k-chunk group
    const int tokw = blockIdx.x * 64 + wid * 16;     // wave's first token
    const int tok  = tokw + lrow;                    // lane's owned token

    // ---- load residual chunks: r[s][i] = z[tok][32s + 8lq + i] ----
    float r[4][8];
    {
        const float* zp = z + (size_t)tok * DIM + 8 * lq;
#pragma unroll
        for (int s = 0; s < 4; ++s) {
            float4 a = *reinterpret_cast<const float4*>(zp + 32 * s);
            float4 b = *reinterpret_cast<const float4*>(zp + 32 * s + 4);
            r[s][0] = a.x; r[s][1] = a.y; r[s][2] = a.z; r[s][3] = a.w;
            r[s][4] = b.x; r[s][5] = b.y; r[s][6] = b.z; r[s][7] = b.w;
        }
    }

    double lsum = 0.0;

    for (int k = 0; k < NUM_CB; ++k) {
        const float* cbk  = cb  + (size_t)k * CB_SIZE * DIM;
        const float* esqk = esq + k * CB_SIZE;

        // ---- split residual into bf16 hi/mid A-fragments ----
        bf16x8 ah[4], am[4];
#pragma unroll
        for (int s = 0; s < 4; ++s) {
#pragma unroll
            for (int i = 0; i < 8; ++i) {
                unsigned short h = bf16_rne(r[s][i]);
                float rem = r[s][i] - bf16_tof(h);
                unsigned short m = bf16_rne(rem);
                ah[s][i] = (short)h;
                am[s][i] = (short)m;
            }
        }

        float m1[4], m2[4];
        int   i1[4];
#pragma unroll
        for (int j = 0; j < 4; ++j) { m1[j] = FLT_MAX; m2[j] = FLT_MAX; i1[j] = 0x7fffffff; }

        for (int T = 0; T < 4; ++T) {         // 64-candidate tiles
            __syncthreads();
            // stage: pure linear float4 copy of precomputed swizzled planes
            {
                const float4* geh4 = reinterpret_cast<const float4*>(g_eh)
                                     + (size_t)(k * 4 + T) * 1024;
                const float4* gel4 = reinterpret_cast<const float4*>(g_el)
                                     + (size_t)(k * 4 + T) * 1024;
                float4* seh4 = reinterpret_cast<float4*>(s_eh);
                float4* sel4 = reinterpret_cast<float4*>(s_el);
#pragma unroll
                for (int i = 0; i < 4; ++i) {
                    seh4[tid + i * 256] = geh4[tid + i * 256];
                    sel4[tid + i * 256] = gel4[tid + i * 256];
                }
            }
            __syncthreads();

            for (int ct = 0; ct < 4; ++ct) {  // 16-candidate column tiles
                const int cbase = ct * 16 + lrow;    // tile-local cand of lane
                bf16x8 bh[4], bl[4];
#pragma unroll
                for (int s = 0; s < 4; ++s) {
                    int ls = (4 * s + lq) ^ lrow;
                    bh[s] = s_eh[cbase * 16 + ls];
                    bl[s] = s_el[cbase * 16 + ls];
                }
                f32x4 acc0 = {0.f, 0.f, 0.f, 0.f};
                f32x4 acc1 = {0.f, 0.f, 0.f, 0.f};
                // rh*eh
                acc0 = __builtin_amdgcn_mfma_f32_16x16x32_bf16(ah[0], bh[0], acc0, 0, 0, 0);
                acc0 = __builtin_amdgcn_mfma_f32_16x16x32_bf16(ah[1], bh[1], acc0, 0, 0, 0);
                acc1 = __builtin_amdgcn_mfma_f32_16x16x32_bf16(ah[2], bh[2], acc1, 0, 0, 0);
                acc1 = __builtin_amdgcn_mfma_f32_16x16x32_bf16(ah[3], bh[3], acc1, 0, 0, 0);
                // rm*eh
                acc0 = __builtin_amdgcn_mfma_f32_16x16x32_bf16(am[0], bh[0], acc0, 0, 0, 0);
                acc0 = __builtin_amdgcn_mfma_f32_16x16x32_bf16(am[1], bh[1], acc0, 0, 0, 0);
                acc1 = __builtin_amdgcn_mfma_f32_16x16x32_bf16(am[2], bh[2], acc1, 0, 0, 0);
                acc1 = __builtin_amdgcn_mfma_f32_16x16x32_bf16(am[3], bh[3], acc1, 0, 0, 0);
                // rh*el
                acc0 = __builtin_amdgcn_mfma_f32_16x16x32_bf16(ah[0], bl[0], acc0, 0, 0, 0);
                acc0 = __builtin_amdgcn_mfma_f32_16x16x32_bf16(ah[1], bl[1], acc0, 0, 0, 0);
                acc1 = __builtin_amdgcn_mfma_f32_16x16x32_bf16(ah[2], bl[2], acc1, 0, 0, 0);
                acc1 = __builtin_amdgcn_mfma_f32_16x16x32_bf16(ah[3], bl[3], acc1, 0, 0, 0);

                const int c = T * 64 + ct * 16 + lrow;      // global candidate
                const float esq_c = esqk[c];
#pragma unroll
                for (int j = 0; j < 4; ++j) {
                    float s = fmaf(-2.0f, acc0[j] + acc1[j], esq_c);
                    if (s < m1[j]) {
                        m2[j] = m1[j]; m1[j] = s; i1[j] = c;
                    } else if (s < m2[j]) {
                        m2[j] = s;
                    }
                }
            }
        }

        // ---- cross-lane top-2 lexicographic reduce (within 16-lane group) --
#pragma unroll
        for (int d = 1; d < 16; d <<= 1) {
#pragma unroll
            for (int j = 0; j < 4; ++j) {
                float om1 = __shfl_xor(m1[j], d);
                float om2 = __shfl_xor(m2[j], d);
                int   oi1 = __shfl_xor(i1[j], d);
                bool ow = (om1 < m1[j]) || (om1 == m1[j] && oi1 < i1[j]);
                float w1 = ow ? om1 : m1[j];
                int   wi = ow ? oi1 : i1[j];
                float lo = ow ? m1[j] : om1;
                float w2 = fminf(fminf(m2[j], om2), lo);
                m1[j] = w1; i1[j] = wi; m2[j] = w2;
            }
        }

        // writers: lane 16*lq + lrow (lrow<4) owns token 4*lq + lrow
        if (lrow < 4) {
            float wm1 = lrow == 0 ? m1[0] : lrow == 1 ? m1[1] : lrow == 2 ? m1[2] : m1[3];
            float wm2 = lrow == 0 ? m2[0] : lrow == 1 ? m2[1] : lrow == 2 ? m2[2] : m2[3];
            int   wc  = lrow == 0 ? i1[0] : lrow == 1 ? i1[1] : lrow == 2 ? i1[2] : i1[3];
            int t = 4 * lq + lrow;
            s_m1[wid][t] = wm1;
            s_m2[wid][t] = wm2;
            s_cmin[wid][t] = wc;
        }
        asm volatile("s_waitcnt lgkmcnt(0)" ::: "memory");

        // ---- Pass B: exact np argmin for ambiguous tokens (wave-coop) ----
        float g1 = s_m1[wid][lrow];
        float g2 = s_m2[wid][lrow];
        bool amb = (lane < 16) && !(g2 - g1 > MARGIN_A);
        unsigned long long mask = __ballot(amb);
        while (mask) {
            int srct = __ffsll(mask) - 1;     // token index 0..15
            mask &= mask - 1;
            if (lrow == srct) {               // 4 owner lanes stage residual
#pragma unroll
                for (int s = 0; s < 4; ++s) {
                    float4* dst = reinterpret_cast<float4*>(
                        &s_rbuf[wid][32 * s + 8 * lq]);
                    dst[0] = make_float4(r[s][0], r[s][1], r[s][2], r[s][3]);
                    dst[1] = make_float4(r[s][4], r[s][5], r[s][6], r[s][7]);
                }
            }
            asm volatile("s_waitcnt lgkmcnt(0)" ::: "memory");
            float xs = 0.f;
            if (lane == 0) xs = np_sum_sq_128(&s_rbuf[wid][0]);
            xs = __shfl(xs, 0);
            const float4* rb4 = reinterpret_cast<const float4*>(&s_rbuf[wid][0]);
            float bd = FLT_MAX;
            int   bc = 0x7fffffff;
#pragma unroll
            for (int ii = 0; ii < 4; ++ii) {
                int c = lane + 64 * ii;
                float dref = np_dist_lds(rb4, xs, esqk[c], cbk + (size_t)c * DIM);
                if (dref < bd || (dref == bd && c < bc)) { bd = dref; bc = c; }
            }
#pragma unroll
            for (int d = 1; d < 64; d <<= 1) {
                float od = __shfl_xor(bd, d);
                int   oc = __shfl_xor(bc, d);
                if (od < bd || (od == bd && oc < bc)) { bd = od; bc = oc; }
            }
            if (lane == 0) s_cmin[wid][srct] = bc;
            asm volatile("s_waitcnt lgkmcnt(0)" ::: "memory");
        }

        // ---- outputs + residual update ----
        if (lane < 16)
            out_idx[(size_t)(tokw + lane) * NUM_CB + k] = (float)s_cmin[wid][lane];

        const int cm = s_cmin[wid][lrow];
        const float* ep = cbk + (size_t)cm * DIM + 8 * lq;
        float l0 = 0.f, l1 = 0.f, l2 = 0.f, l3 = 0.f;
#pragma unroll
        for (int s = 0; s < 4; ++s) {
            float4 ev0 = *reinterpret_cast<const float4*>(ep + 32 * s);
            float4 ev1 = *reinterpret_cast<const float4*>(ep + 32 * s + 4);
            float d0 = ev0.x - r[s][0], d1 = ev0.y - r[s][1];
            float d2 = ev0.z - r[s][2], d3 = ev0.w - r[s][3];
            float d4 = ev1.x - r[s][4], d5 = ev1.y - r[s][5];
            float d6 = ev1.z - r[s][6], d7 = ev1.w - r[s][7];
            l0 = fmaf(d0, d0, l0); l1 = fmaf(d1, d1, l1);
            l2 = fmaf(d2, d2, l2); l3 = fmaf(d3, d3, l3);
            l0 = fmaf(d4, d4, l0); l1 = fmaf(d5, d5, l1);
            l2 = fmaf(d6, d6, l2); l3 = fmaf(d7, d7, l3);
            r[s][0] -= ev0.x; r[s][1] -= ev0.y; r[s][2] -= ev0.z; r[s][3] -= ev0.w;
            r[s][4] -= ev1.x; r[s][5] -= ev1.y; r[s][6] -= ev1.z; r[s][7] -= ev1.w;
        }
        lsum += (double)((l0 + l1) + (l2 + l3));
    }

    // ---- quantized = z - r_final ----
    {
        const float* zp = z + (size_t)tok * DIM + 8 * lq;
        float* op = out_q + (size_t)tok * DIM + 8 * lq;
#pragma unroll
        for (int s = 0; s < 4; ++s) {
            float4 a = *reinterpret_cast<const float4*>(zp + 32 * s);
            float4 b = *reinterpret_cast<const float4*>(zp + 32 * s + 4);
            float4 qa = make_float4(a.x - r[s][0], a.y - r[s][1],
                                    a.z - r[s][2], a.w - r[s][3]);
            float4 qb = make_float4(b.x - r[s][4], b.y - r[s][5],
                                    b.z - r[s][6], b.w - r[s][7]);
            *reinterpret_cast<float4*>(op + 32 * s)     = qa;
            *reinterpret_cast<float4*>(op + 32 * s + 4) = qb;
        }
    }

    // ---- loss reduction ----
    for (int off = 32; off > 0; off >>= 1)
        lsum += __shfl_down(lsum, off, 64);
    __shared__ double wsum[4];
    if (lane == 0) wsum[wid] = lsum;
    __syncthreads();
    if (tid == 0)
        atomicAdd(loss_acc, (wsum[0] + wsum[1]) + (wsum[2] + wsum[3]));
}

__global__ void rvq_finalize_kernel(const double* __restrict__ loss_acc,
                                    float* __restrict__ out_loss) {
    out_loss[0] = (float)(1.25 * loss_acc[0] / (double)Q_ELEMS);
}

extern "C" void kernel_launch(void* const* d_in, const int* in_sizes, int n_in,
                              void* d_out, int out_size, void* d_ws, size_t ws_size,
                              hipStream_t stream) {
    const float* z  = (const float*)d_in[0];
    const float* cb = (const float*)d_in[1];

    float* out_q    = (float*)d_out;
    float* out_idx  = out_q + Q_ELEMS;
    float* out_loss = out_idx + I_ELEMS;

    double* loss_acc = (double*)d_ws;
    float*  esq      = (float*)((char*)d_ws + 256);
    bf16x8* g_eh     = (bf16x8*)((char*)d_ws + 16384);            // 512 KB
    bf16x8* g_el     = (bf16x8*)((char*)d_ws + 16384 + 524288);   // 512 KB

    hipMemsetAsync(loss_acc, 0, sizeof(double), stream);
    rvq_esq_kernel<<<(NUM_CB * CB_SIZE + 255) / 256, 256, 0, stream>>>(cb, esq);
    rvq_split_kernel<<<(NUM_CB * CB_SIZE * 16 + 255) / 256, 256, 0, stream>>>(
        cb, g_eh, g_el);
    rvq_mfma_kernel<<<BT / 64, 256, 0, stream>>>(z, cb, esq, g_eh, g_el,
                                                 out_q, out_idx, loss_acc);
    rvq_finalize_kernel<<<1, 1, 0, stream>>>(loss_acc, out_loss);
}